// Round 1
// 1057.978 us; speedup vs baseline: 1.1055x; 1.1055x over previous
//
#include <hip/hip_runtime.h>
#include <math.h>

typedef _Float16 f16;
typedef f16 f16x8 __attribute__((ext_vector_type(8)));
typedef float f32x4 __attribute__((ext_vector_type(4)));

#define B_ 8
#define D_ 256
#define T_ 8192
#define NQ 8
#define KB 1024
#define TT 64
#define NTHR 256
#define SCALE_UP 2048.0f
#define SCALE_DN 4.8828125e-4f        // 2^-11

#define OUT_CODES (B_ * D_ * T_)      // 16777216
#define OUT_BW (OUT_CODES + NQ * B_ * T_)
#define OUT_LOSS (OUT_BW + 1)

// rs: 64 rows x 512 halves (h1 granules 0..31, h2s granules 32..63),
// granule (8 halves) swizzled: stored at g ^ (t & 7). No pad.
#define R_BYTES 65536
#define RED_OFF R_BYTES               // redv[256] f32
#define REDI_OFF (RED_OFF + 1024)     // redi[256] i32
#define SEL_OFF (REDI_OFF + 1024)     // sel[64]
#define WSUM_OFF (SEL_OFF + 256)
#define LDS_TOTAL (WSUM_OFF + 16)     // 67856 -> 2 blocks/CU

// workspace layout
#define WS_HI (8192 * 4)              // csq first (32KB)
#define CBW_HALVES (NQ * 8 * KB * 32) // 2,097,152 halves per array
#define WS_LO (WS_HI + CBW_HALVES * 2)

// ---------------- init: codebook row norms (fp32) + scalar outputs ----------------
__global__ void init_cbsq_kernel(const float* __restrict__ cb, const int* __restrict__ sr,
                                 float* __restrict__ csq, float* __restrict__ out) {
    int gid = blockIdx.x * blockDim.x + threadIdx.x;
    int row = gid >> 6;
    int lane = gid & 63;
    float4 v = ((const float4*)(cb + (size_t)row * D_))[lane];
    float s = fmaf(v.x, v.x, fmaf(v.y, v.y, fmaf(v.z, v.z, v.w * v.w)));
#pragma unroll
    for (int off = 32; off; off >>= 1) s += __shfl_down(s, off);
    if (lane == 0) csq[row] = s;
    if (gid == 0) {
        out[OUT_BW] = (float)(*sr) * (80.0f / 1000.0f);
        out[OUT_LOSS] = 0.0f;
    }
}

// ---------------- init: split codebook into f16 hi + scaled-lo, [q][dc8][code][32] ----------------
__global__ void init_split_kernel(const float* __restrict__ cb, f16* __restrict__ whi,
                                  f16* __restrict__ wlo) {
    int gid = blockIdx.x * 256 + threadIdx.x;   // (q*8+dc)*1024 + k
    int qdc = gid >> 10, k = gid & 1023;
    int q = qdc >> 3, dc = qdc & 7;
    const float* src = cb + ((size_t)(q * 1024 + k)) * 256 + dc * 32;
    size_t wo = (size_t)gid * 32;
#pragma unroll
    for (int jj = 0; jj < 4; ++jj) {
        float4 a = ((const float4*)src)[jj * 2];
        float4 c = ((const float4*)src)[jj * 2 + 1];
        float vals[8] = {a.x, a.y, a.z, a.w, c.x, c.y, c.z, c.w};
        f16x8 hv, lv;
#pragma unroll
        for (int i = 0; i < 8; ++i) {
            f16 h = (f16)vals[i];
            hv[i] = h;
            lv[i] = (f16)((vals[i] - (float)h) * SCALE_UP);   // scaled lo: no f16 underflow
        }
        *(f16x8*)&whi[wo + jj * 8] = hv;
        *(f16x8*)&wlo[wo + jj * 8] = lv;
    }
}

// ---------------- main RVQ kernel: 3-product split-f16 MFMA GEMM, B direct from L2 ----------------
// dot = hi*hi + 2^-11*(loS*hi + hi*loS). The ll term (al*bl ~ 1e-4 abs on dists of
// O(100)) is below the fp32-accumulation noise floor (~2e-4 over 256-chain) -> dropped.
extern "C" __global__ __launch_bounds__(NTHR, 2)
void rvq_kernel(const float* __restrict__ x, const float* __restrict__ cb,
                const float* __restrict__ csq, const f16* __restrict__ whi,
                const f16* __restrict__ wlo, float* __restrict__ out) {
    extern __shared__ char smem[];
    f16* rs = (f16*)smem;                          // [64][512] halves, granule-swizzled
    float* redv = (float*)(smem + RED_OFF);
    int* redi = (int*)(smem + REDI_OFF);
    int* sel = (int*)(smem + SEL_OFF);
    float* wsum = (float*)(smem + WSUM_OFF);

    const int tid = threadIdx.x;
    const int w = tid >> 6;
    const int l = tid & 63;
    const int l15 = l & 15;
    const int q4 = l >> 4;

    const int b = blockIdx.x >> 7;
    const int t0 = (blockIdx.x & 127) * TT;
    const float* xb = x + (size_t)b * D_ * T_;

    // residual init: rs[t][d] split of x[b][d][t0+t] (coalesced over t); swizzled store
    for (int d = tid >> 6; d < D_; d += 4) {
        float v = xb[(size_t)d * T_ + t0 + l];
        f16 h = (f16)v;
        const int sw = l & 7;
        rs[l * 512 + (((d >> 3) ^ sw) << 3) + (d & 7)] = h;
        rs[l * 512 + ((((d >> 3) + 32) ^ sw) << 3) + (d & 7)] = (f16)((v - (float)h) * SCALE_UP);
    }

    float ssq = 0.0f;

    for (int q = 0; q < NQ; ++q) {
        const float* cbq = cb + (size_t)q * KB * D_;
        const char* wq = (const char*)(whi + (size_t)q * 8 * KB * 32);
        const char* lq = (const char*)(wlo + (size_t)q * 8 * KB * 32);

        __syncthreads();   // rs ready (init or prev-q update); redv/redi free for this q

        // cross-sweep running best, per-lane registers (slot = (mt,rg) row ownership,
        // sweep-invariant; codes ascend across sweeps -> strict < keeps first min)
        float bval[16];
        int bidx[16];
#pragma unroll
        for (int e = 0; e < 16; ++e) { bval[e] = INFINITY; bidx[e] = 0; }

        for (int s = 0; s < 4; ++s) {              // 4 sweeps of 256 codes; wave stripe = 64
            // per-lane byte offsets into [code][32] tile: code*64 + q4*16
            int voff[4];
#pragma unroll
            for (int nt = 0; nt < 4; ++nt)
                voff[nt] = (s * 256 + w * 64 + nt * 16 + l15) * 64 + q4 * 16;

            f32x4 ah[4][4], am[4][4];              // 128 acc VGPRs
#pragma unroll
            for (int mt = 0; mt < 4; ++mt)
#pragma unroll
                for (int nt = 0; nt < 4; ++nt) { ah[mt][nt] = (f32x4)0.0f; am[mt][nt] = (f32x4)0.0f; }

            // B-frag software pipeline: cur in registers, next prefetched during MFMA
            f16x8 cb1[4], cb2[4];
#pragma unroll
            for (int nt = 0; nt < 4; ++nt) {
                cb1[nt] = *(const f16x8*)(wq + voff[nt]);
                cb2[nt] = *(const f16x8*)(lq + voff[nt]);
            }

#pragma unroll 1
            for (int dc = 0; dc < 8; ++dc) {
                f16x8 nb1[4], nb2[4];
                if (dc < 7) {
                    const char* bp1 = wq + (dc + 1) * 65536;
                    const char* bp2 = lq + (dc + 1) * 65536;
#pragma unroll
                    for (int nt = 0; nt < 4; ++nt) {
                        nb1[nt] = *(const f16x8*)(bp1 + voff[nt]);
                        nb2[nt] = *(const f16x8*)(bp2 + voff[nt]);
                    }
                }
                const int ga = dc * 4 + q4;        // h1 granule (h2s = +32)
#pragma unroll
                for (int mt = 0; mt < 4; ++mt) {
                    const int t = mt * 16 + l15;
                    const f16* rowp = rs + t * 512;
                    const int sw = t & 7;
                    f16x8 af1 = *(const f16x8*)&rowp[(ga ^ sw) << 3];
                    f16x8 af2 = *(const f16x8*)&rowp[((ga + 32) ^ sw) << 3];
#pragma unroll
                    for (int nt = 0; nt < 4; ++nt) {
                        ah[mt][nt] = __builtin_amdgcn_mfma_f32_16x16x32_f16(af1, cb1[nt], ah[mt][nt], 0, 0, 0);
                        am[mt][nt] = __builtin_amdgcn_mfma_f32_16x16x32_f16(af2, cb1[nt], am[mt][nt], 0, 0, 0);
                        am[mt][nt] = __builtin_amdgcn_mfma_f32_16x16x32_f16(af1, cb2[nt], am[mt][nt], 0, 0, 0);
                    }
                }
                if (dc < 7) {
#pragma unroll
                    for (int nt = 0; nt < 4; ++nt) { cb1[nt] = nb1[nt]; cb2[nt] = nb2[nt]; }
                }
            }
            // fold sweep into cross-sweep per-lane best (codes ascending -> strict <)
            const int cbase = s * 256 + w * 64 + l15;
#pragma unroll
            for (int nt = 0; nt < 4; ++nt) {
                const int code = cbase + nt * 16;
                const float cq = csq[q * KB + code];
#pragma unroll
                for (int mt = 0; mt < 4; ++mt)
#pragma unroll
                    for (int rg = 0; rg < 4; ++rg) {
                        const float dot = fmaf(am[mt][nt][rg], SCALE_DN, ah[mt][nt][rg]);
                        const float dist = fmaf(-2.0f, dot, cq);
                        const int e = mt * 4 + rg;
                        if (dist < bval[e]) { bval[e] = dist; bidx[e] = code; }
                    }
            }
        }
        // once per q: butterfly across the 16 lanes sharing each t
#pragma unroll
        for (int m = 1; m < 16; m <<= 1) {
#pragma unroll
            for (int e = 0; e < 16; ++e) {
                const float ov = __shfl_xor(bval[e], m);
                const int oi = __shfl_xor(bidx[e], m);
                if (ov < bval[e] || (ov == bval[e] && oi < bidx[e])) { bval[e] = ov; bidx[e] = oi; }
            }
        }
        if (l15 == 0) {
#pragma unroll
            for (int mt = 0; mt < 4; ++mt)
#pragma unroll
                for (int rg = 0; rg < 4; ++rg) {
                    const int t = mt * 16 + q4 * 4 + rg;   // C-layout row ownership
                    redv[w * 64 + t] = bval[mt * 4 + rg];
                    redi[w * 64 + t] = bidx[mt * 4 + rg];
                }
        }
        __syncthreads();   // all waves' redv/redi final
        if (tid < TT) {
            float bv = redv[tid];
            int bi = redi[tid];
#pragma unroll
            for (int w2 = 1; w2 < 4; ++w2) {
                const float v = redv[w2 * 64 + tid];
                const int ii = redi[w2 * 64 + tid];
                if (v < bv || (v == bv && ii < bi)) { bv = v; bi = ii; }
            }
            sel[tid] = bi;
            out[OUT_CODES + ((size_t)q * B_ + b) * T_ + t0 + tid] = (float)bi;
        }
        __syncthreads();   // sel ready; all K-loop rs reads long done
        // residual update: fp32 = h1 + h2s*2^-11, subtract cb row, re-split; ssq
        {
            const int t = tid & 63, ch = tid >> 6;  // row t, 64-half chunk ch
            const float* crow = cbq + (size_t)sel[t] * D_ + ch * 64;
            f16* rowp = rs + t * 512;
            const int sw = t & 7;
#pragma unroll
            for (int jj = 0; jj < 8; ++jj) {
                const int g1 = ((ch * 8 + jj) ^ sw) << 3;
                const int g2 = ((ch * 8 + jj + 32) ^ sw) << 3;
                f16x8 hv = *(const f16x8*)&rowp[g1];
                f16x8 lv = *(const f16x8*)&rowp[g2];
                const float4 c0 = *(const float4*)&crow[jj * 8];
                const float4 c1 = *(const float4*)&crow[jj * 8 + 4];
                const float cc[8] = {c0.x, c0.y, c0.z, c0.w, c1.x, c1.y, c1.z, c1.w};
                f16x8 nh, nl;
#pragma unroll
                for (int i = 0; i < 8; ++i) {
                    const float r = fmaf((float)lv[i], SCALE_DN, (float)hv[i]);
                    const float nv = r - cc[i];
                    ssq = fmaf(nv, nv, ssq);
                    const f16 h = (f16)nv;
                    nh[i] = h;
                    nl[i] = (f16)((nv - (float)h) * SCALE_UP);
                }
                *(f16x8*)&rowp[g1] = nh;
                *(f16x8*)&rowp[g2] = nl;
            }
        }
        // next q's top __syncthreads orders rs writes before A-frag reads
    }
    __syncthreads();
    // quantized = x - r_final, [B][D][T], coalesced over t
    {
        float* outq = out + (size_t)b * D_ * T_;
        for (int d = tid >> 6; d < D_; d += 4) {
            const int sw = l & 7;
            const float h1 = (float)rs[l * 512 + (((d >> 3) ^ sw) << 3) + (d & 7)];
            const float h2 = (float)rs[l * 512 + ((((d >> 3) + 32) ^ sw) << 3) + (d & 7)];
            const size_t gi = (size_t)d * T_ + t0 + l;
            outq[gi] = xb[gi] - fmaf(h2, SCALE_DN, h1);
        }
    }
    // commit loss: wave reduce -> block reduce -> one atomic
#pragma unroll
    for (int off = 32; off; off >>= 1) ssq += __shfl_down(ssq, off);
    if (l == 0) wsum[w] = ssq;
    __syncthreads();
    if (tid == 0) {
        const float scale = 0.25f / ((float)NQ * (float)B_ * (float)D_ * (float)T_);
        atomicAdd(out + OUT_LOSS, (wsum[0] + wsum[1] + wsum[2] + wsum[3]) * scale);
    }
}

extern "C" void kernel_launch(void* const* d_in, const int* in_sizes, int n_in,
                              void* d_out, int out_size, void* d_ws, size_t ws_size,
                              hipStream_t stream) {
    const float* x = (const float*)d_in[0];
    const int* sr = (const int*)d_in[1];
    const float* cb = (const float*)d_in[2];
    float* out = (float*)d_out;
    float* csq = (float*)d_ws;
    f16* whi = (f16*)((char*)d_ws + WS_HI);
    f16* wlo = (f16*)((char*)d_ws + WS_LO);

    hipFuncSetAttribute((const void*)rvq_kernel, hipFuncAttributeMaxDynamicSharedMemorySize,
                        LDS_TOTAL);

    init_cbsq_kernel<<<2048, 256, 0, stream>>>(cb, sr, csq, out);
    init_split_kernel<<<256, 256, 0, stream>>>(cb, whi, wlo);
    rvq_kernel<<<B_ * (T_ / TT), NTHR, LDS_TOTAL, stream>>>(x, cb, csq, whi, wlo, out);
}